// Round 8
// baseline (324.996 us; speedup 1.0000x reference)
//
#include <hip/hip_runtime.h>
#include <hip/hip_bf16.h>

#define NUM_HEADS 4
#define HD 256
#define QD 256
#define VD 256
#define B_SZ 32
#define N_NODES 8192
#define NEG_SLOPE 0.2f

typedef short bf16x8 __attribute__((ext_vector_type(8)));
typedef float f32x4 __attribute__((ext_vector_type(4)));

static __device__ __forceinline__ unsigned short f2bf(float f) {
    __hip_bfloat16 h = __float2bfloat16(f);
    return *reinterpret_cast<unsigned short*>(&h);
}

// ---------------------------------------------------------------------------
// Kernel 1: prep
//  blocks 0..31 : hqb[b][col] = query[b]@Wq[:,col] + 2*bq[col]
//  blocks 32..63: pack Wq -> bf16 fragment order
// ---------------------------------------------------------------------------
__global__ __launch_bounds__(256)
void prep_kernel(const float* __restrict__ query,
                 const float* __restrict__ Wq,
                 const float* __restrict__ bq,
                 unsigned short* __restrict__ WqP,
                 float* __restrict__ hqb) {
    int blk = blockIdx.x;
    int tid = threadIdx.x;
    if (blk < 32) {
        int b = blk, col = tid;
        float acc = 2.0f * bq[col];
#pragma unroll 16
        for (int k = 0; k < QD; ++k)
            acc += query[b * QD + k] * Wq[k * HD + col];
        hqb[b * HD + col] = acc;
    } else {
        int idx = blk - 32;
        int kstep = idx >> 2, g = idx & 3;
        int col = tid;
        unsigned short v[8];
#pragma unroll
        for (int j = 0; j < 8; ++j)
            v[j] = f2bf(Wq[(kstep * 32 + g * 8 + j) * HD + col]);
        *reinterpret_cast<uint4*>(WqP + kstep * 8192 + col * 32 + g * 8) =
            *reinterpret_cast<uint4*>(v);
    }
}

// ---------------------------------------------------------------------------
// Kernel 2 (FUSED, barrier-free): grid 4096 = (b, 64-row block-chunk).
// Wave w independently owns 16 rows: stage own key slice -> MFMA all 4 heads
// (two 2-head passes) -> epilogue -> wave-local softmax (m,l over 16 rows)
// -> PV from global. Single end-of-block rendezvous combines 4 wave partials
// into one 64-row chunk partial (rescaled). NO barriers before that.
// ---------------------------------------------------------------------------
__global__ __launch_bounds__(256)
void fused_kernel(const float* __restrict__ key,
                  const float* __restrict__ value,
                  const unsigned short* __restrict__ WqP,
                  const float* __restrict__ hqb,
                  const float* __restrict__ avec,
                  float* __restrict__ s,
                  float* __restrict__ p_part,
                  float* __restrict__ pml) {
    __shared__ __align__(16) unsigned short kt[64][264];   // 33792 B, per-wave 16-row slices
    __shared__ float ese[4][4][16];                        // [w][h][n] exp scores
    __shared__ float mwl[4][4], lwl[4][4];                 // per-wave m,l
    float (*red)[4][256] = reinterpret_cast<float(*)[4][256]>(&kt[0][0]);  // alias kt (post-barrier)

    int bid = blockIdx.x;
    int b = bid >> 7, cb = bid & 127;
    int tid = threadIdx.x;
    int w = tid >> 6, lane = tid & 63;
    int col16 = lane & 15, g = lane >> 4;
    int n0 = cb * 64 + w * 16;

    // ---- stage own 16 rows x 256 cols: 16 float4 loads issued back-to-back
    {
        const float* kb = key + ((size_t)(b * N_NODES + n0)) * QD;
        f32x4 kv[16];
#pragma unroll
        for (int i = 0; i < 16; ++i) {
            int row = (i >> 2) * 4 + (lane >> 4);
            int col = (i & 3) * 64 + (lane & 15) * 4;
            kv[i] = *reinterpret_cast<const f32x4*>(kb + row * QD + col);
        }
#pragma unroll
        for (int i = 0; i < 16; ++i) {
            int row = (i >> 2) * 4 + (lane >> 4);
            int col = (i & 3) * 64 + (lane & 15) * 4;
            unsigned int u0, u1;
            asm("v_cvt_pk_bf16_f32 %0, %1, %2" : "=v"(u0) : "v"(kv[i][0]), "v"(kv[i][1]));
            asm("v_cvt_pk_bf16_f32 %0, %1, %2" : "=v"(u1) : "v"(kv[i][2]), "v"(kv[i][3]));
            uint2 st = {u0, u1};
            *reinterpret_cast<uint2*>(&kt[w * 16 + row][col]) = st;
        }
    }

    // ---- two passes of 2 heads each (keeps VGPR ~100)
#pragma unroll
    for (int p = 0; p < 2; ++p) {
        f32x4 acc[2][4];
#pragma unroll
        for (int i = 0; i < 2; ++i)
#pragma unroll
            for (int j = 0; j < 4; ++j)
                acc[i][j] = (f32x4){0.f, 0.f, 0.f, 0.f};

#pragma unroll
        for (int ks = 0; ks < 8; ++ks) {
            bf16x8 afr = *reinterpret_cast<const bf16x8*>(&kt[w * 16 + col16][ks * 32 + g * 8]);
#pragma unroll
            for (int hh = 0; hh < 2; ++hh) {
                const unsigned short* wp = WqP + ks * 8192 + (p * 2 + hh) * 2048 + g * 8;
#pragma unroll
                for (int ct = 0; ct < 4; ++ct) {
                    bf16x8 bfr = *reinterpret_cast<const bf16x8*>(wp + (ct * 16 + col16) * 32);
                    acc[hh][ct] = __builtin_amdgcn_mfma_f32_16x16x32_bf16(afr, bfr, acc[hh][ct], 0, 0, 0);
                }
            }
        }

        // epilogue + wave-local softmax per head
#pragma unroll
        for (int hh = 0; hh < 2; ++hh) {
            int h = p * 2 + hh;
            float part[4] = {0.f, 0.f, 0.f, 0.f};
#pragma unroll
            for (int ct = 0; ct < 4; ++ct) {
                float hq_ = hqb[b * HD + h * 64 + ct * 16 + col16];
                float av = avec[ct * 16 + col16];
#pragma unroll
                for (int r = 0; r < 4; ++r) {
                    float pre = acc[hh][ct][r] + hq_;
                    float t = fmaxf(pre, NEG_SLOPE * pre);
                    part[r] += av * t;
                }
            }
#pragma unroll
            for (int off = 1; off < 16; off <<= 1)
#pragma unroll
                for (int r = 0; r < 4; ++r)
                    part[r] += __shfl_xor(part[r], off, 64);

            // raw score store: rows g*4..g*4+3 contiguous -> float4
            if (col16 == 0) {
                float4 sv4 = {part[0], part[1], part[2], part[3]};
                *reinterpret_cast<float4*>(
                    s + ((size_t)(b * NUM_HEADS + h)) * N_NODES + n0 + g * 4) = sv4;
            }

            // softmax over this wave's 16 rows (2 shfls)
            float m = fmaxf(fmaxf(part[0], part[1]), fmaxf(part[2], part[3]));
            m = fmaxf(m, __shfl_xor(m, 16, 64));
            m = fmaxf(m, __shfl_xor(m, 32, 64));
            float ep[4];
            float l = 0.f;
#pragma unroll
            for (int r = 0; r < 4; ++r) { ep[r] = __expf(part[r] - m); l += ep[r]; }
            l += __shfl_xor(l, 16, 64);
            l += __shfl_xor(l, 32, 64);
            if (col16 == 0) {
                float4 e4 = {ep[0], ep[1], ep[2], ep[3]};
                *reinterpret_cast<float4*>(&ese[w][h][g * 4]) = e4;
            }
            if (lane == 0) { mwl[w][h] = m; lwl[w][h] = l; }
        }
    }

    // ---- PV: stream own 16 value rows from global (coalesced 1KB/inst)
    f32x4 a[4];
#pragma unroll
    for (int h = 0; h < 4; ++h) a[h] = (f32x4){0.f, 0.f, 0.f, 0.f};
    {
        const float* vb = value + ((size_t)(b * N_NODES + n0)) * VD + lane * 4;
#pragma unroll
        for (int n = 0; n < 16; ++n) {
            f32x4 v = *reinterpret_cast<const f32x4*>(vb + (size_t)n * VD);
#pragma unroll
            for (int h = 0; h < 4; ++h) a[h] += ese[w][h][n] * v;
        }
    }

    // ---- end-of-block rendezvous: combine 4 wave partials (rescale to block M)
    __syncthreads();   // all waves done reading their kt slices (red aliases kt)
#pragma unroll
    for (int h = 0; h < 4; ++h)
        *reinterpret_cast<f32x4*>(&red[w][h][lane * 4]) = a[h];
    __syncthreads();

#pragma unroll
    for (int h = 0; h < 4; ++h) {
        float M = fmaxf(fmaxf(mwl[0][h], mwl[1][h]), fmaxf(mwl[2][h], mwl[3][h]));
        float acc = 0.f, lsum = 0.f;
#pragma unroll
        for (int w4 = 0; w4 < 4; ++w4) {
            float f = __expf(mwl[w4][h] - M);
            acc += red[w4][h][tid] * f;
            lsum += lwl[w4][h] * f;
        }
        p_part[((size_t)(b * 128 + cb)) * 1024 + h * 256 + tid] = acc;
        if (tid == 0) {
            pml[((size_t)(b * 128 + cb)) * 8 + h] = M;
            pml[((size_t)(b * 128 + cb)) * 8 + 4 + h] = lsum;
        }
    }
}

// ---------------------------------------------------------------------------
// Kernel 3: final. Per (b,h): global M,L over 128 chunks; rescale-reduce
// p_part; @Wv + bias + relu; emit (M, invL) for epass.
// ---------------------------------------------------------------------------
__global__ __launch_bounds__(256)
void final_kernel(const float* __restrict__ p_part,
                  const float* __restrict__ pml,
                  const float* __restrict__ Wv,
                  const float* __restrict__ bv,
                  float* __restrict__ hout,
                  float* __restrict__ sc) {
    int bh = blockIdx.x;
    int b = bh >> 2, h = bh & 3;
    int tid = threadIdx.x;
    int wv = tid >> 6, lane = tid & 63;

    float mc = -1e30f, lc = 0.f;
    if (tid < 128) {
        mc = pml[((size_t)(b * 128 + tid)) * 8 + h];
        lc = pml[((size_t)(b * 128 + tid)) * 8 + 4 + h];
    }

    __shared__ float r4a[4], r4b[4];
    float M = mc;
#pragma unroll
    for (int off = 1; off < 64; off <<= 1) M = fmaxf(M, __shfl_xor(M, off, 64));
    if (lane == 0) r4a[wv] = M;
    __syncthreads();
    M = fmaxf(fmaxf(r4a[0], r4a[1]), fmaxf(r4a[2], r4a[3]));

    __shared__ float wfs[256];
    float wf = (tid < 128) ? __expf(mc - M) : 0.f;
    wfs[tid] = wf;
    float Lp = wf * lc;
#pragma unroll
    for (int off = 1; off < 64; off <<= 1) Lp += __shfl_xor(Lp, off, 64);
    if (lane == 0) r4b[wv] = Lp;
    __syncthreads();
    float L = r4b[0] + r4b[1] + r4b[2] + r4b[3];
    float invL = 1.0f / L;
    if (tid == 0) {
        sc[bh * 2] = M;
        sc[bh * 2 + 1] = invL;
    }

    float acc = 0.f;
    const float* pp = p_part + ((size_t)(b * 128)) * 1024 + h * 256 + tid;
#pragma unroll 8
    for (int c = 0; c < 128; ++c)
        acc += wfs[c] * pp[(size_t)c * 1024];
    __shared__ float ps[256];
    ps[tid] = acc * invL;
    __syncthreads();

    int d = tid & 63, kr = tid >> 6;
    float a2 = 0.f;
#pragma unroll 8
    for (int k = kr * 64; k < kr * 64 + 64; ++k)
        a2 += ps[k] * Wv[k * HD + h * 64 + d];
    __shared__ float rs[4][64];
    rs[kr][d] = a2;
    __syncthreads();
    if (tid < 64) {
        float o = bv[h * 64 + tid] + rs[0][tid] + rs[1][tid] + rs[2][tid] + rs[3][tid];
        hout[b * HD + h * 64 + tid] = fmaxf(o, 0.f);
    }
}

// ---------------------------------------------------------------------------
// Kernel 4: e-pass. e_out[b,n,h] = exp(s[b,h,n]-M)*invL.
// ---------------------------------------------------------------------------
__global__ __launch_bounds__(256)
void epass_kernel(const float* __restrict__ s,
                  const float* __restrict__ sc,
                  float* __restrict__ e_out) {
    int bid = blockIdx.x;
    int b = bid >> 5, t = bid & 31;
    int n = t * 256 + threadIdx.x;
    float4 ev;
#pragma unroll
    for (int h = 0; h < 4; ++h) {
        float M = sc[(b * 4 + h) * 2];
        float invL = sc[(b * 4 + h) * 2 + 1];
        float sv = s[((size_t)(b * 4 + h)) * N_NODES + n];
        (&ev.x)[h] = __expf(sv - M) * invL;
    }
    *reinterpret_cast<float4*>(e_out + ((size_t)(b * N_NODES + n)) * 4) = ev;
}

extern "C" void kernel_launch(void* const* d_in, const int* in_sizes, int n_in,
                              void* d_out, int out_size, void* d_ws, size_t ws_size,
                              hipStream_t stream) {
    const float* query = (const float*)d_in[0];
    const float* key   = (const float*)d_in[1];
    const float* value = (const float*)d_in[2];
    const float* Wq    = (const float*)d_in[3];
    const float* bq    = (const float*)d_in[4];
    const float* Wv    = (const float*)d_in[5];
    const float* bv    = (const float*)d_in[6];
    const float* avec  = (const float*)d_in[7];
    float* out = (float*)d_out;

    char* ws = (char*)d_ws;
    unsigned short* WqP = (unsigned short*)ws;               // 128 KB
    float* hqb    = (float*)(ws + 131072);                   // 32 KB
    float* s      = (float*)(ws + 163840);                   // 4 MB
    float* pml    = (float*)(ws + 4358144);                  // 128 KB
    float* sc     = (float*)(ws + 4489216);                  // 1 KB
    float* p_part = (float*)(ws + 4493312);                  // 16 MB

    prep_kernel<<<64, 256, 0, stream>>>(query, Wq, bq, WqP, hqb);
    fused_kernel<<<B_SZ * 128, 256, 0, stream>>>(key, value, WqP, hqb, avec, s, p_part, pml);
    final_kernel<<<B_SZ * NUM_HEADS, 256, 0, stream>>>(p_part, pml, Wv, bv, out, sc);
    epass_kernel<<<B_SZ * 32, 256, 0, stream>>>(s, sc, out + B_SZ * HD);
}

// Round 9
// 158.537 us; speedup vs baseline: 2.0500x; 2.0500x over previous
//
#include <hip/hip_runtime.h>
#include <hip/hip_bf16.h>

#define NUM_HEADS 4
#define HD 256
#define QD 256
#define VD 256
#define B_SZ 32
#define N_NODES 8192
#define NEG_SLOPE 0.2f

typedef short bf16x8 __attribute__((ext_vector_type(8)));
typedef float f32x4 __attribute__((ext_vector_type(4)));

static __device__ __forceinline__ unsigned short f2bf(float f) {
    __hip_bfloat16 h = __float2bfloat16(f);
    return *reinterpret_cast<unsigned short*>(&h);
}

// ---------------------------------------------------------------------------
// Kernel 1: prep
//  blocks 0..31 : hqb[b][col] = query[b]@Wq[:,col] + 2*bq[col]
//  blocks 32..63: pack Wq -> bf16 fragment order
// ---------------------------------------------------------------------------
__global__ __launch_bounds__(256)
void prep_kernel(const float* __restrict__ query,
                 const float* __restrict__ Wq,
                 const float* __restrict__ bq,
                 unsigned short* __restrict__ WqP,
                 float* __restrict__ hqb) {
    int blk = blockIdx.x;
    int tid = threadIdx.x;
    if (blk < 32) {
        int b = blk, col = tid;
        float acc = 2.0f * bq[col];
#pragma unroll 16
        for (int k = 0; k < QD; ++k)
            acc += query[b * QD + k] * Wq[k * HD + col];
        hqb[b * HD + col] = acc;
    } else {
        int idx = blk - 32;
        int kstep = idx >> 2, g = idx & 3;
        int col = tid;
        unsigned short v[8];
#pragma unroll
        for (int j = 0; j < 8; ++j)
            v[j] = f2bf(Wq[(kstep * 32 + g * 8 + j) * HD + col]);
        *reinterpret_cast<uint4*>(WqP + kstep * 8192 + col * 32 + g * 8) =
            *reinterpret_cast<uint4*>(v);
    }
}

// ---------------------------------------------------------------------------
// Kernel 2 (FUSED, Wq-stationary): grid 2048 = (b, 128-row chunk), 512 thr.
// Stage full WqP (128 KB) in LDS once; barrier; then each wave independent:
// key rows as reg A-frags -> 4 heads x 32 MFMA (B via ds_read_b128) ->
// epilogue + wave-local softmax in registers -> value burst -> PV ->
// end-of-block reduce (red aliases wq after barrier).
// ---------------------------------------------------------------------------
__global__ __launch_bounds__(512)
void fused_kernel(const float* __restrict__ key,
                  const float* __restrict__ value,
                  const unsigned short* __restrict__ WqP,
                  const float* __restrict__ hqb,
                  const float* __restrict__ avec,
                  float* __restrict__ s,
                  float* __restrict__ p_part,
                  float* __restrict__ pml) {
    __shared__ __align__(16) unsigned short wq[65536];   // 128 KB (red/aux alias later)

    int bid = blockIdx.x;
    int b = bid >> 6, cb = bid & 63;
    int tid = threadIdx.x;
    int w = tid >> 6, lane = tid & 63;
    int col16 = lane & 15, g = (lane >> 4) & 3;
    int n0 = cb * 128 + w * 16;

    // ---- stage full WqP -> LDS (identical fragment layout)
    {
        const uint4* src = reinterpret_cast<const uint4*>(WqP);
        uint4* dst = reinterpret_cast<uint4*>(wq);
#pragma unroll
        for (int j = 0; j < 16; ++j)
            dst[tid + j * 512] = src[tid + j * 512];
    }
    __syncthreads();

    // ---- my 16 key rows -> A-fragments in registers
    // lane (col16,g) needs key[n0+col16][ks*32+g*8 .. +8] for ks=0..7
    bf16x8 a[8];
    {
        const float* kb = key + ((size_t)(b * N_NODES + n0 + col16)) * QD + g * 8;
#pragma unroll
        for (int half = 0; half < 2; ++half) {
            f32x4 kf[8];
#pragma unroll
            for (int k2 = 0; k2 < 4; ++k2) {
                kf[k2 * 2]     = *reinterpret_cast<const f32x4*>(kb + (half * 4 + k2) * 32);
                kf[k2 * 2 + 1] = *reinterpret_cast<const f32x4*>(kb + (half * 4 + k2) * 32 + 4);
            }
#pragma unroll
            for (int k2 = 0; k2 < 4; ++k2) {
                unsigned int u0, u1, u2, u3;
                asm("v_cvt_pk_bf16_f32 %0, %1, %2" : "=v"(u0) : "v"(kf[k2*2][0]), "v"(kf[k2*2][1]));
                asm("v_cvt_pk_bf16_f32 %0, %1, %2" : "=v"(u1) : "v"(kf[k2*2][2]), "v"(kf[k2*2][3]));
                asm("v_cvt_pk_bf16_f32 %0, %1, %2" : "=v"(u2) : "v"(kf[k2*2+1][0]), "v"(kf[k2*2+1][1]));
                asm("v_cvt_pk_bf16_f32 %0, %1, %2" : "=v"(u3) : "v"(kf[k2*2+1][2]), "v"(kf[k2*2+1][3]));
                uint4 t = {u0, u1, u2, u3};
                a[half * 4 + k2] = *reinterpret_cast<bf16x8*>(&t);
            }
        }
    }

    float av4[4];
#pragma unroll
    for (int ct = 0; ct < 4; ++ct) av4[ct] = avec[ct * 16 + col16];

    // ---- per-head: MFMA (B from LDS) + epilogue + wave-local softmax (regs)
    float epv[4][4];           // [h][r] exp scores for my rows g*4+r
    float mreg[4], lreg[4];
#pragma unroll
    for (int h = 0; h < 4; ++h) {
        f32x4 acc[4];
#pragma unroll
        for (int ct = 0; ct < 4; ++ct) acc[ct] = (f32x4){0.f, 0.f, 0.f, 0.f};
#pragma unroll
        for (int ks = 0; ks < 8; ++ks) {
            const unsigned short* wp = wq + ks * 8192 + h * 2048 + g * 8;
#pragma unroll
            for (int ct = 0; ct < 4; ++ct) {
                bf16x8 bf = *reinterpret_cast<const bf16x8*>(wp + (ct * 16 + col16) * 32);
                acc[ct] = __builtin_amdgcn_mfma_f32_16x16x32_bf16(a[ks], bf, acc[ct], 0, 0, 0);
            }
        }
        float part[4] = {0.f, 0.f, 0.f, 0.f};
#pragma unroll
        for (int ct = 0; ct < 4; ++ct) {
            float hq_ = hqb[b * HD + h * 64 + ct * 16 + col16];
#pragma unroll
            for (int r = 0; r < 4; ++r) {
                float pre = acc[ct][r] + hq_;
                float t = fmaxf(pre, NEG_SLOPE * pre);
                part[r] += av4[ct] * t;
            }
        }
#pragma unroll
        for (int off = 1; off < 16; off <<= 1)
#pragma unroll
            for (int r = 0; r < 4; ++r)
                part[r] += __shfl_xor(part[r], off, 64);
        if (col16 == 0) {
            float4 sv4 = {part[0], part[1], part[2], part[3]};
            *reinterpret_cast<float4*>(
                s + ((size_t)(b * NUM_HEADS + h)) * N_NODES + n0 + g * 4) = sv4;
        }
        float m = fmaxf(fmaxf(part[0], part[1]), fmaxf(part[2], part[3]));
        m = fmaxf(m, __shfl_xor(m, 16, 64));
        m = fmaxf(m, __shfl_xor(m, 32, 64));
        float l = 0.f;
#pragma unroll
        for (int r = 0; r < 4; ++r) { epv[h][r] = __expf(part[r] - m); l += epv[h][r]; }
        l += __shfl_xor(l, 16, 64);
        l += __shfl_xor(l, 32, 64);
        mreg[h] = m;
        lreg[h] = l;
    }

    // ---- value burst: 16 x contiguous-1KB instructions
    f32x4 vv[16];
    {
        const float* vb = value + ((size_t)(b * N_NODES + n0)) * VD + lane * 4;
#pragma unroll
        for (int n = 0; n < 16; ++n)
            vv[n] = *reinterpret_cast<const f32x4*>(vb + (size_t)n * VD);
    }

    // ---- PV: ep broadcast via constant-lane shfl (row n lives in g = n>>2)
    f32x4 pa[4];
#pragma unroll
    for (int h = 0; h < 4; ++h) pa[h] = (f32x4){0.f, 0.f, 0.f, 0.f};
#pragma unroll
    for (int n = 0; n < 16; ++n) {
#pragma unroll
        for (int h = 0; h < 4; ++h) {
            float e = __shfl(epv[h][n & 3], (n >> 2) * 16, 64);
            pa[h] += e * vv[n];
        }
    }

    // ---- end-of-block: alias wq as reduce buffer, combine 8 wave partials
    __syncthreads();   // all wq (MFMA) reads retired
    float (*red)[4][256] = reinterpret_cast<float(*)[4][256]>(wq);
    float* mwlp = reinterpret_cast<float*>(wq) + 8 * 4 * 256;   // [8][4]
    float* lwlp = mwlp + 32;                                    // [8][4]
#pragma unroll
    for (int h = 0; h < 4; ++h)
        *reinterpret_cast<f32x4*>(&red[w][h][lane * 4]) = pa[h];
    if (lane == 0) {
#pragma unroll
        for (int h = 0; h < 4; ++h) { mwlp[w * 4 + h] = mreg[h]; lwlp[w * 4 + h] = lreg[h]; }
    }
    __syncthreads();

    for (int i = tid; i < 1024; i += 512) {
        int h = i >> 8, k = i & 255;
        float M = -1e30f;
#pragma unroll
        for (int w8 = 0; w8 < 8; ++w8) M = fmaxf(M, mwlp[w8 * 4 + h]);
        float acc = 0.f, ls = 0.f;
#pragma unroll
        for (int w8 = 0; w8 < 8; ++w8) {
            float f = __expf(mwlp[w8 * 4 + h] - M);
            acc += red[w8][h][k] * f;
            ls += lwlp[w8 * 4 + h] * f;
        }
        p_part[(size_t)bid * 1024 + i] = acc;
        if (k == 0) {
            pml[(size_t)bid * 8 + h] = M;
            pml[(size_t)bid * 8 + 4 + h] = ls;
        }
    }
}

// ---------------------------------------------------------------------------
// Kernel 3: final. Per (b,h): global M,L over 64 chunks; rescale-reduce
// p_part; @Wv + bias + relu; emit (M, invL) for epass.
// ---------------------------------------------------------------------------
__global__ __launch_bounds__(256)
void final_kernel(const float* __restrict__ p_part,
                  const float* __restrict__ pml,
                  const float* __restrict__ Wv,
                  const float* __restrict__ bv,
                  float* __restrict__ hout,
                  float* __restrict__ sc) {
    int bh = blockIdx.x;
    int b = bh >> 2, h = bh & 3;
    int tid = threadIdx.x;
    int wv = tid >> 6, lane = tid & 63;

    float mc = -1e30f, lc = 0.f;
    if (tid < 64) {
        mc = pml[((size_t)(b * 64 + tid)) * 8 + h];
        lc = pml[((size_t)(b * 64 + tid)) * 8 + 4 + h];
    }

    __shared__ float r4a[4], r4b[4];
    __shared__ float wfs[64];
    float M = mc;
#pragma unroll
    for (int off = 1; off < 64; off <<= 1) M = fmaxf(M, __shfl_xor(M, off, 64));
    if (lane == 0) r4a[wv] = M;
    __syncthreads();
    M = fmaxf(fmaxf(r4a[0], r4a[1]), fmaxf(r4a[2], r4a[3]));

    float wf = (tid < 64) ? __expf(mc - M) : 0.f;
    if (tid < 64) wfs[tid] = wf;
    float Lp = wf * lc;
#pragma unroll
    for (int off = 1; off < 64; off <<= 1) Lp += __shfl_xor(Lp, off, 64);
    if (lane == 0) r4b[wv] = Lp;
    __syncthreads();
    float L = r4b[0] + r4b[1] + r4b[2] + r4b[3];
    float invL = 1.0f / L;
    if (tid == 0) {
        sc[bh * 2] = M;
        sc[bh * 2 + 1] = invL;
    }

    float acc = 0.f;
    const float* pp = p_part + ((size_t)(b * 64)) * 1024 + h * 256 + tid;
#pragma unroll 8
    for (int c = 0; c < 64; ++c)
        acc += wfs[c] * pp[(size_t)c * 1024];
    __shared__ float ps[256];
    ps[tid] = acc * invL;
    __syncthreads();

    int d = tid & 63, kr = tid >> 6;
    float a2 = 0.f;
#pragma unroll 8
    for (int k = kr * 64; k < kr * 64 + 64; ++k)
        a2 += ps[k] * Wv[k * HD + h * 64 + d];
    __shared__ float rs[4][64];
    rs[kr][d] = a2;
    __syncthreads();
    if (tid < 64) {
        float o = bv[h * 64 + tid] + rs[0][tid] + rs[1][tid] + rs[2][tid] + rs[3][tid];
        hout[b * HD + h * 64 + tid] = fmaxf(o, 0.f);
    }
}

// ---------------------------------------------------------------------------
// Kernel 4: e-pass. e_out[b,n,h] = exp(s[b,h,n]-M)*invL.
// ---------------------------------------------------------------------------
__global__ __launch_bounds__(256)
void epass_kernel(const float* __restrict__ s,
                  const float* __restrict__ sc,
                  float* __restrict__ e_out) {
    int bid = blockIdx.x;
    int b = bid >> 5, t = bid & 31;
    int n = t * 256 + threadIdx.x;
    float4 ev;
#pragma unroll
    for (int h = 0; h < 4; ++h) {
        float M = sc[(b * 4 + h) * 2];
        float invL = sc[(b * 4 + h) * 2 + 1];
        float sv = s[((size_t)(b * 4 + h)) * N_NODES + n];
        (&ev.x)[h] = __expf(sv - M) * invL;
    }
    *reinterpret_cast<float4*>(e_out + ((size_t)(b * N_NODES + n)) * 4) = ev;
}

extern "C" void kernel_launch(void* const* d_in, const int* in_sizes, int n_in,
                              void* d_out, int out_size, void* d_ws, size_t ws_size,
                              hipStream_t stream) {
    const float* query = (const float*)d_in[0];
    const float* key   = (const float*)d_in[1];
    const float* value = (const float*)d_in[2];
    const float* Wq    = (const float*)d_in[3];
    const float* bq    = (const float*)d_in[4];
    const float* Wv    = (const float*)d_in[5];
    const float* bv    = (const float*)d_in[6];
    const float* avec  = (const float*)d_in[7];
    float* out = (float*)d_out;

    char* ws = (char*)d_ws;
    unsigned short* WqP = (unsigned short*)ws;               // 128 KB
    float* hqb    = (float*)(ws + 131072);                   // 32 KB
    float* s      = (float*)(ws + 163840);                   // 4 MB
    float* pml    = (float*)(ws + 4358144);                  // 64 KB
    float* sc     = (float*)(ws + 4423680);                  // 4 KB
    float* p_part = (float*)(ws + 4427776);                  // 8 MB

    prep_kernel<<<64, 256, 0, stream>>>(query, Wq, bq, WqP, hqb);
    fused_kernel<<<2048, 512, 0, stream>>>(key, value, WqP, hqb, avec, s, p_part, pml);
    final_kernel<<<B_SZ * NUM_HEADS, 256, 0, stream>>>(p_part, pml, Wv, bv, out, sc);
    epass_kernel<<<B_SZ * 32, 256, 0, stream>>>(s, sc, out + B_SZ * HD);
}